// Round 7
// baseline (15358.592 us; speedup 1.0000x reference)
//
#include <hip/hip_runtime.h>
#include <stdint.h>
#include <math.h>

// ---------------------------------------------------------------------------
// QuantumDiffusionDreamer — round 7: r5 core (measured best, 9.42 ms) +
// G7 fused with the DDPM update. G7 uses the operand-SWAPPED MFMA (lane holds
// 4 consecutive C-columns of one row) so the update fusion is fully
// vectorized: float4 x-read, 8B d0/d1 reads, float4 x-write, 8B xbf-write.
// Eliminates the update dispatch + itf materialization (5 dispatches/step).
// PRNG: JAX threefry2x32 partitionable (verified r1-r6). x stays fp32.
// ---------------------------------------------------------------------------

typedef __bf16 bf16x8 __attribute__((ext_vector_type(8)));
typedef float floatx4 __attribute__((ext_vector_type(4)));
typedef unsigned int uintx2 __attribute__((ext_vector_type(2)));

__host__ __device__ inline void tf2x32(uint32_t k0, uint32_t k1,
                                       uint32_t x0, uint32_t x1,
                                       uint32_t& o0, uint32_t& o1) {
  uint32_t ks2 = k0 ^ k1 ^ 0x1BD11BDAu;
#define TF_R(r) { x0 += x1; x1 = (x1 << (r)) | (x1 >> (32 - (r))); x1 ^= x0; }
  x0 += k0; x1 += k1;
  TF_R(13) TF_R(15) TF_R(26) TF_R(6)
  x0 += k1;  x1 += ks2 + 1u;
  TF_R(17) TF_R(29) TF_R(16) TF_R(24)
  x0 += ks2; x1 += k0 + 2u;
  TF_R(13) TF_R(15) TF_R(26) TF_R(6)
  x0 += k0;  x1 += k1 + 3u;
  TF_R(17) TF_R(29) TF_R(16) TF_R(24)
  x0 += k1;  x1 += ks2 + 4u;
  TF_R(13) TF_R(15) TF_R(26) TF_R(6)
  x0 += ks2; x1 += k0 + 5u;
#undef TF_R
  o0 = x0; o1 = x1;
}

__device__ inline float erfinv_f32(float x) {
  float w = -log1pf(-x * x);
  float p;
  if (w < 5.0f) {
    w = w - 2.5f;
    p = 2.81022636e-08f;
    p = fmaf(p, w, 3.43273939e-07f);
    p = fmaf(p, w, -3.5233877e-06f);
    p = fmaf(p, w, -4.39150654e-06f);
    p = fmaf(p, w, 0.00021858087f);
    p = fmaf(p, w, -0.00125372503f);
    p = fmaf(p, w, -0.00417768164f);
    p = fmaf(p, w, 0.246640727f);
    p = fmaf(p, w, 1.50140941f);
  } else {
    w = sqrtf(w) - 3.0f;
    p = -0.000200214257f;
    p = fmaf(p, w, 0.000100950558f);
    p = fmaf(p, w, 0.00134934322f);
    p = fmaf(p, w, -0.00367342844f);
    p = fmaf(p, w, 0.00573950773f);
    p = fmaf(p, w, -0.0076224613f);
    p = fmaf(p, w, 0.00943887047f);
    p = fmaf(p, w, 1.00167406f);
    p = fmaf(p, w, 2.83297682f);
  }
  return p * x;
}

__device__ inline float tf_normal(uint32_t k0, uint32_t k1, uint32_t i) {
  uint32_t o0, o1;
  tf2x32(k0, k1, 0u, i, o0, o1);
  uint32_t bits = o0 ^ o1;  // partitionable random_bits path
  float f = __uint_as_float(0x3F800000u | (bits >> 9)) - 1.0f;  // [0,1)
  float u = f * 2.0f + (-0.99999994f);
  u = fmaxf(-0.99999994f, u);
  return 1.41421356f * erfinv_f32(u);
}

__device__ inline unsigned short f2bf(float f) {
  uint32_t u = __float_as_uint(f);
  u += 0x7FFFu + ((u >> 16) & 1u);   // round-to-nearest-even
  return (unsigned short)(u >> 16);
}
__device__ inline float bf2f(unsigned short h) {
  return __uint_as_float(((uint32_t)h) << 16);
}
__device__ inline uintx2 pack4bf(float a, float b, float c, float d) {
  uintx2 r;
  r.x = (uint32_t)f2bf(a) | ((uint32_t)f2bf(b) << 16);
  r.y = (uint32_t)f2bf(c) | ((uint32_t)f2bf(d) << 16);
  return r;
}
// extract bf16 element r (0..3) from an 8B pack
__device__ inline float bfx(uintx2 p, int r) {
  uint32_t w = (r < 2) ? p.x : p.y;
  return bf2f((unsigned short)((r & 1) ? (w >> 16) : (w & 0xffffu)));
}

// ---------------------------------------------------------------------------
// Weight transpose + bf16 convert: Wt[n][k] = bf16(W[k][n]);  W is [K,N] fp32.
// ---------------------------------------------------------------------------
__global__ __launch_bounds__(256)
void transpose_bf16_kernel(const float* __restrict__ W,
                           unsigned short* __restrict__ Wt, int K, int N) {
  __shared__ float tile[32][33];
  int kb = blockIdx.x * 32, nb = blockIdx.y * 32;
  int tx = threadIdx.x & 31, ty = threadIdx.x >> 5;
#pragma unroll
  for (int i = 0; i < 32; i += 8)
    tile[ty + i][tx] = W[(size_t)(kb + ty + i) * N + nb + tx];
  __syncthreads();
#pragma unroll
  for (int i = 0; i < 32; i += 8)
    Wt[(size_t)(nb + ty + i) * K + kb + tx] = f2bf(tile[tx][ty + i]);
}

// ---------------------------------------------------------------------------
// Double-buffered MFMA core (r5-identical for SWAP=false).
// SWAP=false: acc[u][v] = mfma(a[u], b[v]); lane (fm,quad) holds
//   C[row0+wr*64+u*16+quad*4+r][col0+wc*64+v*16+fm]          (r5 epilogue)
// SWAP=true : acc[v][u] = mfma(b[v], a[u]); lane (fm,quad) holds
//   C[row0+wr*64+u*16+fm][col0+wc*64+v*16+quad*4+r]          (4 consecutive
//   columns per lane -> 8B/16B-vectorizable epilogue)
// 128x128 tile, BK=32, 4 waves, 16x16x32 bf16 MFMA, global_load_lds(16B),
// raw `s_waitcnt vmcnt(4); s_barrier` keeps next tile's loads in flight.
// ---------------------------------------------------------------------------
template<bool SWAP>
__device__ __forceinline__ void gemm_core_db(
    const unsigned short* __restrict__ A0, const unsigned short* __restrict__ A1,
    int lda0, int lda1, int K0, int Ktot,
    const unsigned short* __restrict__ Bt,
    int row0, int col0,
    unsigned short (*As)[128 * 32], unsigned short (*Bs)[128 * 32],
    floatx4 (&acc)[4][4]) {
  const int tid = threadIdx.x;
  const int wave = tid >> 6, lane = tid & 63;
  const int wr = wave >> 1, wc = wave & 1;
  const int lrow = lane >> 2;       // 0..15
  const int lk = (lane & 3) * 8;    // 0,8,16,24
  const int fm = lane & 15, quad = lane >> 4;

  auto issue = [&](int kt, int buf) {
    const int k0 = kt * 32;
    const unsigned short* Ap; int kOff, lda;
    if (k0 < K0) { Ap = A0; kOff = k0; lda = lda0; }
    else         { Ap = A1; kOff = k0 - K0; lda = lda1; }
#pragma unroll
    for (int r = 0; r < 2; r++) {
      int srow = r * 64 + wave * 16 + lrow;   // lane-contiguous LDS order
      __builtin_amdgcn_global_load_lds(
          (const __attribute__((address_space(1))) uint32_t*)
              (Ap + (size_t)(row0 + srow) * lda + kOff + lk),
          (__attribute__((address_space(3))) uint32_t*)(&As[buf][srow * 32 + lk]),
          16, 0, 0);
      __builtin_amdgcn_global_load_lds(
          (const __attribute__((address_space(1))) uint32_t*)
              (Bt + (size_t)(col0 + srow) * Ktot + k0 + lk),
          (__attribute__((address_space(3))) uint32_t*)(&Bs[buf][srow * 32 + lk]),
          16, 0, 0);
    }
  };

  const int nk = Ktot >> 5;
  issue(0, 0);
  for (int k = 0; k < nk; k++) {
    const int cur = k & 1;
    if (k + 1 < nk) {
      issue(k + 1, cur ^ 1);
      asm volatile("s_waitcnt vmcnt(4)\ns_barrier" ::: "memory");
    } else {
      asm volatile("s_waitcnt vmcnt(0)\ns_barrier" ::: "memory");
    }
    bf16x8 a[4], b[4];
#pragma unroll
    for (int u = 0; u < 4; u++)
      a[u] = *(const bf16x8*)(&As[cur][(wr * 64 + u * 16 + fm) * 32 + quad * 8]);
#pragma unroll
    for (int v = 0; v < 4; v++)
      b[v] = *(const bf16x8*)(&Bs[cur][(wc * 64 + v * 16 + fm) * 32 + quad * 8]);
    if constexpr (!SWAP) {
#pragma unroll
      for (int u = 0; u < 4; u++)
#pragma unroll
        for (int v = 0; v < 4; v++)
          acc[u][v] = __builtin_amdgcn_mfma_f32_16x16x32_bf16(a[u], b[v],
                                                              acc[u][v], 0, 0, 0);
    } else {
#pragma unroll
      for (int v = 0; v < 4; v++)
#pragma unroll
        for (int u = 0; u < 4; u++)
          acc[v][u] = __builtin_amdgcn_mfma_f32_16x16x32_bf16(b[v], a[u],
                                                              acc[v][u], 0, 0, 0);
    }
    asm volatile("s_barrier" ::: "memory");
  }
}

// XCD-aware swizzle: gy is always 64 (M=8192). by = id%64, bx = id/64 makes
// all col-blocks of one row-block share id%8 -> same XCD (performance-only).
__device__ __forceinline__ void swizzled_block(int& row0, int& col0) {
  int id = blockIdx.x + gridDim.x * blockIdx.y;
  row0 = (id & 63) << 7;
  col0 = (id >> 6) << 7;
}

// Generic GEMM (r5 epilogue). ACT: 0 none, 1 relu, 2 tanh, 3 gelu(exact),
// 4 = split: cols < nsplit -> relu+bias0 -> C0; else tanh+bias1 -> C1.
template<int ACT>
__global__ __launch_bounds__(256)
void mfma_gemm(const unsigned short* __restrict__ A0,
               const unsigned short* __restrict__ A1,
               int lda0, int lda1, int K0, int Ktot,
               const unsigned short* __restrict__ Bt,
               const float* __restrict__ bias0,
               const float* __restrict__ bias1, int nsplit,
               unsigned short* __restrict__ C0,
               unsigned short* __restrict__ C1, int ldc) {
  __shared__ unsigned short As[2][128 * 32];
  __shared__ unsigned short Bs[2][128 * 32];
  int row0, col0;
  swizzled_block(row0, col0);
  floatx4 acc[4][4];
#pragma unroll
  for (int u = 0; u < 4; u++)
#pragma unroll
    for (int v = 0; v < 4; v++) acc[u][v] = (floatx4){0.f, 0.f, 0.f, 0.f};
  gemm_core_db<false>(A0, A1, lda0, lda1, K0, Ktot, Bt, row0, col0, As, Bs, acc);

  const int lane = threadIdx.x & 63, wave = threadIdx.x >> 6;
  const int wr = wave >> 1, wc = wave & 1;
  const int fm = lane & 15, quad = lane >> 4;
  const bool side = (ACT == 4) && (col0 >= nsplit);
  const float* bias = side ? bias1 : bias0;
  unsigned short* C = side ? C1 : C0;
  const int cbase = col0 - (side ? nsplit : 0);
#pragma unroll
  for (int v = 0; v < 4; v++) {
    int col = cbase + wc * 64 + v * 16 + fm;
    float bv = bias[col];
#pragma unroll
    for (int u = 0; u < 4; u++) {
      int rbase = row0 + wr * 64 + u * 16 + quad * 4;
#pragma unroll
      for (int r = 0; r < 4; r++) {
        float val = acc[u][v][r] + bv;
        if (ACT == 1) val = fmaxf(val, 0.0f);
        if (ACT == 2) val = tanhf(val);
        if (ACT == 3) val = 0.5f * val * (1.0f + erff(val * 0.70710678118654752f));
        if (ACT == 4) val = side ? tanhf(val) : fmaxf(val, 0.0f);
        C[(size_t)(rbase + r) * ldc + col] = f2bf(val);
      }
    }
  }
}

// z-batched pair of independent GEMMs (same shapes). No activation. (r5)
__global__ __launch_bounds__(256)
void mfma_gemm_pair(const unsigned short* __restrict__ Aa,
                    const unsigned short* __restrict__ Ab,
                    const unsigned short* __restrict__ Bta,
                    const unsigned short* __restrict__ Btb,
                    const float* __restrict__ biasa,
                    const float* __restrict__ biasb,
                    unsigned short* __restrict__ Ca,
                    unsigned short* __restrict__ Cb,
                    int Ktot, int ldc) {
  __shared__ unsigned short As[2][128 * 32];
  __shared__ unsigned short Bs[2][128 * 32];
  const int z = blockIdx.z;
  const unsigned short* A = z ? Ab : Aa;
  const unsigned short* Bt = z ? Btb : Bta;
  const float* bias = z ? biasb : biasa;
  unsigned short* C = z ? Cb : Ca;
  int row0, col0;
  swizzled_block(row0, col0);
  floatx4 acc[4][4];
#pragma unroll
  for (int u = 0; u < 4; u++)
#pragma unroll
    for (int v = 0; v < 4; v++) acc[u][v] = (floatx4){0.f, 0.f, 0.f, 0.f};
  gemm_core_db<false>(A, A, Ktot, Ktot, Ktot, Ktot, Bt, row0, col0, As, Bs, acc);

  const int lane = threadIdx.x & 63, wave = threadIdx.x >> 6;
  const int wr = wave >> 1, wc = wave & 1;
  const int fm = lane & 15, quad = lane >> 4;
#pragma unroll
  for (int v = 0; v < 4; v++) {
    int col = col0 + wc * 64 + v * 16 + fm;
    float bv = bias[col];
#pragma unroll
    for (int u = 0; u < 4; u++) {
      int rbase = row0 + wr * 64 + u * 16 + quad * 4;
#pragma unroll
      for (int r = 0; r < 4; r++)
        C[(size_t)(rbase + r) * ldc + col] = f2bf(acc[u][v][r] + bv);
    }
  }
}

// G7 fused: itf = hi @ Wi2 + bi2 (SWAPPED layout), then full DDPM x-update
// in the epilogue. Per lane-(u,v): 4 consecutive columns of one row ->
// float4 x-read, 8B d0/d1 reads, float4 x-write, 8B xbf-write.
__global__ __launch_bounds__(256)
void mfma_gemm_update(const unsigned short* __restrict__ A,   // hi [8192,1024]
                      const unsigned short* __restrict__ Bt,  // Wi2_t [512][1024]
                      const float* __restrict__ bias,         // bi2
                      const unsigned short* __restrict__ d0,
                      const unsigned short* __restrict__ d1,
                      float* __restrict__ x,
                      unsigned short* __restrict__ xbf,
                      const float* __restrict__ a_amp,
                      const float* __restrict__ b_amp,
                      const float* __restrict__ ph,
                      float coh, float c1, float sqa, float sigma,
                      int add_noise, uint32_t k0, uint32_t k1) {
  __shared__ unsigned short As[2][128 * 32];
  __shared__ unsigned short Bs[2][128 * 32];
  int row0, col0;
  swizzled_block(row0, col0);
  floatx4 acc[4][4];
#pragma unroll
  for (int v = 0; v < 4; v++)
#pragma unroll
    for (int u = 0; u < 4; u++) acc[v][u] = (floatx4){0.f, 0.f, 0.f, 0.f};
  gemm_core_db<true>(A, A, 1024, 1024, 1024, 1024, Bt, row0, col0, As, Bs, acc);

  float aa = a_amp[0], bb = b_amp[0], pc = ph[0];
  float a2 = aa * aa, b2 = bb * bb, s = a2 + b2;
  float p0 = a2 / s, p1 = b2 / s;
  float sp0 = sqrtf(p0), sp1 = sqrtf(p1);
  float qi = 2.0f * sqrtf(p0 * p1) * pc * coh;
  float nscale = sigma + 0.1f * fabsf(qi);
  float inv_sqa = 1.0f / sqa;

  const int lane = threadIdx.x & 63, wave = threadIdx.x >> 6;
  const int wr = wave >> 1, wc = wave & 1;
  const int fm = lane & 15, quad = lane >> 4;
  const int cbase = col0 + wc * 64 + quad * 4;
#pragma unroll
  for (int v = 0; v < 4; v++) {
    int colb = cbase + v * 16;
    floatx4 bv = *(const floatx4*)(bias + colb);
#pragma unroll
    for (int u = 0; u < 4; u++) {
      int row = row0 + wr * 64 + u * 16 + fm;
      size_t base = (size_t)row * 512 + colb;
      uintx2 d0p = *(const uintx2*)(d0 + base);
      uintx2 d1p = *(const uintx2*)(d1 + base);
      floatx4 xv = *(const floatx4*)(x + base);
      floatx4 xn;
#pragma unroll
      for (int r = 0; r < 4; r++) {
        float itf = acc[v][u][r] + bv[r];
        float den = sp0 * bfx(d0p, r) + sp1 * bfx(d1p, r) + qi * itf;
        float val = (xv[r] - c1 * den) * inv_sqa;
        if (add_noise)
          val += nscale * tf_normal(k0, k1, (uint32_t)(base + (size_t)r));
        xn[r] = val;
      }
      *(floatx4*)(x + base) = xn;
      *(uintx2*)(xbf + base) = pack4bf(xn[0], xn[1], xn[2], xn[3]);
    }
  }
}

__global__ void init_normal_kernel(float* __restrict__ x,
                                   unsigned short* __restrict__ xbf,
                                   uint32_t k0, uint32_t k1, int n) {
  int i = blockIdx.x * blockDim.x + threadIdx.x;
  if (i >= n) return;
  float v = tf_normal(k0, k1, (uint32_t)i);
  x[i] = v;
  xbf[i] = f2bf(v);
}

__global__ void final_kernel(const float* __restrict__ x,
                             const float* __restrict__ real,
                             float* __restrict__ out,
                             const float* __restrict__ a_amp,
                             const float* __restrict__ b_amp,
                             uint32_t k0, uint32_t k1, int n) {
  int i = blockIdx.x * blockDim.x + threadIdx.x;
  if (i >= n) return;
  float aa = a_amp[0], bb = b_amp[0];
  float a2 = aa * aa, b2 = bb * bb;
  float p0 = a2 / (a2 + b2);
  uint32_t o0, o1;
  tf2x32(k0, k1, 0u, 0u, o0, o1);
  uint32_t bits = o0 ^ o1;
  float u = __uint_as_float(0x3F800000u | (bits >> 9)) - 1.0f;
  float xv = x[i];
  out[i] = (u < p0) ? (0.7f * xv + 0.3f * real[i]) : xv;
}

extern "C" void kernel_launch(void* const* d_in, const int* in_sizes, int n_in,
                              void* d_out, int out_size, void* d_ws,
                              size_t ws_size, hipStream_t stream) {
  const float* real = (const float*)d_in[0];
  const float* Wq  = (const float*)d_in[2];
  const float* bq  = (const float*)d_in[3];
  const float* W01 = (const float*)d_in[4];
  const float* b01 = (const float*)d_in[5];
  const float* W02 = (const float*)d_in[6];
  const float* b02 = (const float*)d_in[7];
  const float* W11 = (const float*)d_in[8];
  const float* b11 = (const float*)d_in[9];
  const float* W12 = (const float*)d_in[10];
  const float* b12 = (const float*)d_in[11];
  const float* Wi1 = (const float*)d_in[12];
  const float* bi1 = (const float*)d_in[13];
  const float* Wi2 = (const float*)d_in[14];
  const float* bi2 = (const float*)d_in[15];
  const float* a_amp = (const float*)d_in[16];
  const float* b_amp = (const float*)d_in[17];
  const float* ph    = (const float*)d_in[18];

  const int Nn = 8192, F = 512, H = 1024;
  const int nElem = Nn * F;  // 4,194,304
  const int NSPLIT_OFF = 1 << 30;

  // workspace layout
  char* ws = (char*)d_ws;
  float* x = (float*)ws;                                   ws += (size_t)nElem * 4;
  unsigned short* xbf = (unsigned short*)ws;               ws += (size_t)nElem * 2;
  unsigned short* qf  = (unsigned short*)ws;               ws += (size_t)Nn * H * 2;
  unsigned short* h0  = (unsigned short*)ws;               ws += (size_t)Nn * H * 2;
  unsigned short* h1  = (unsigned short*)ws;               ws += (size_t)Nn * H * 2;
  unsigned short* d0  = (unsigned short*)ws;               ws += (size_t)nElem * 2;
  unsigned short* d1  = (unsigned short*)ws;               ws += (size_t)nElem * 2;
  unsigned short* Wq_t  = (unsigned short*)ws;             ws += (size_t)F * H * 2;
  unsigned short* WA_t  = (unsigned short*)ws;             ws += (size_t)(2 * H) * H * 2; // [W01_t ; W11_t]
  unsigned short* W02_t = (unsigned short*)ws;             ws += (size_t)H * F * 2;
  unsigned short* W12_t = (unsigned short*)ws;             ws += (size_t)H * F * 2;
  unsigned short* Wi1_t = (unsigned short*)ws;             ws += (size_t)(2 * F) * H * 2;
  unsigned short* Wi2_t = (unsigned short*)ws;             ws += (size_t)H * F * 2;

  dim3 tb(256);
  transpose_bf16_kernel<<<dim3(F / 32, H / 32), tb, 0, stream>>>(Wq, Wq_t, F, H);
  transpose_bf16_kernel<<<dim3(H / 32, H / 32), tb, 0, stream>>>(W01, WA_t, H, H);
  transpose_bf16_kernel<<<dim3(H / 32, H / 32), tb, 0, stream>>>(W11, WA_t + (size_t)H * H, H, H);
  transpose_bf16_kernel<<<dim3(H / 32, F / 32), tb, 0, stream>>>(W02, W02_t, H, F);
  transpose_bf16_kernel<<<dim3(H / 32, F / 32), tb, 0, stream>>>(W12, W12_t, H, F);
  transpose_bf16_kernel<<<dim3(2 * F / 32, H / 32), tb, 0, stream>>>(Wi1, Wi1_t, 2 * F, H);
  transpose_bf16_kernel<<<dim3(H / 32, F / 32), tb, 0, stream>>>(Wi2, Wi2_t, H, F);

  uint32_t kx0, kx1; tf2x32(0u, 1u, 0u, 10000u, kx0, kx1);
  init_normal_kernel<<<(nElem + 255) / 256, 256, 0, stream>>>(x, xbf, kx0, kx1, nElem);

  float sched[100];
  for (int i = 0; i < 100; i++)
    sched[i] = (float)(1e-4 + (0.02 - 1e-4) * (double)i / 99.0);
  const float decay = expf(-0.1f);
  float coh = 1.0f;

  dim3 blk(256);
  dim3 g1(H / 128, 64);            // 512 blocks
  dim3 g2(2 * H / 128, 64);        // 1024 blocks
  dim3 g45(F / 128, 64, 2);        // 512 blocks
  dim3 g6(H / 128, 64);            // 512 blocks
  dim3 g7(F / 128, 64);            // 256 blocks

  for (int j = 0; j < 50; j++) {
    int t = 49 - j;
    // G1: qf = relu(x @ Wq + bq)
    mfma_gemm<1><<<g1, blk, 0, stream>>>(xbf, xbf, F, F, F, F, Wq_t,
                                         bq, nullptr, NSPLIT_OFF, qf, nullptr, H);
    // G2 merged: h0 = relu(qf@W01+b01), h1 = tanh(qf@W11+b11), N=2048 GEMM
    mfma_gemm<4><<<g2, blk, 0, stream>>>(qf, qf, H, H, H, H, WA_t,
                                         b01, b11, H, h0, h1, H);
    // G4/G5 z-batched: d0 = h0@W02+b02 ; d1 = h1@W12+b12
    mfma_gemm_pair<<<g45, blk, 0, stream>>>(h0, h1, W02_t, W12_t, b02, b12,
                                            d0, d1, H, F);
    // G6: qf(reused) = gelu([d0|d1] @ Wi1 + bi1)
    mfma_gemm<3><<<g6, blk, 0, stream>>>(d0, d1, F, F, F, 2 * F, Wi1_t,
                                         bi1, nullptr, NSPLIT_OFF, qf, nullptr, H);

    float schedt = sched[t];
    float alphaf = fmaxf(1.0f - schedt, 1e-8f);
    float one_m_alpha = 1.0f - alphaf;
    float sqrt_1ma = sqrtf(fmaxf(one_m_alpha, 1e-8f));
    float c1 = one_m_alpha / sqrt_1ma;
    float sqa = sqrtf(alphaf);
    float sigma = 0.0f;
    if (t > 0) {
      float ap = 1.0f - sched[t - 1];
      sigma = sqrtf(fmaxf((1.0f - ap) / one_m_alpha * (1.0f - alphaf / ap), 0.0f));
    }
    uint32_t kt0, kt1; tf2x32(0u, 1u, 0u, (uint32_t)t, kt0, kt1);
    // G7 fused: itf = qf @ Wi2 + bi2  +  DDPM update of x/xbf
    mfma_gemm_update<<<g7, blk, 0, stream>>>(
        qf, Wi2_t, bi2, d0, d1, x, xbf, a_amp, b_amp, ph, coh, c1, sqa, sigma,
        (t > 0) ? 1 : 0, kt0, kt1);
    coh *= decay;
  }

  uint32_t ku0, ku1; tf2x32(0u, 1u, 0u, 99999u, ku0, ku1);
  final_kernel<<<(nElem + 255) / 256, 256, 0, stream>>>(
      x, real, (float*)d_out, a_amp, b_amp, ku0, ku1, nElem);
}

// Round 8
// 10151.419 us; speedup vs baseline: 1.5130x; 1.5130x over previous
//
#include <hip/hip_runtime.h>
#include <stdint.h>
#include <math.h>

// ---------------------------------------------------------------------------
// QuantumDiffusionDreamer — round 8: r5 structure (measured best 9.42 ms)
// with the MFMA core switched 16x16x32 -> 32x32x16 (2382 vs 2075 TF ubench).
// Per wave per K=32 iter: 8 mfma_32x32x16 (64.6 cyc) vs 16 mfma_16x16x32
// (77.6 cyc); same LDS traffic, same 64 acc VGPRs. Standalone update_kernel
// (r7 lesson: PRNG needs high occupancy, never in a GEMM epilogue).
// PRNG: JAX threefry2x32 partitionable (verified r1-r7). x stays fp32.
// ---------------------------------------------------------------------------

typedef __bf16 bf16x8 __attribute__((ext_vector_type(8)));
typedef float floatx16 __attribute__((ext_vector_type(16)));

__host__ __device__ inline void tf2x32(uint32_t k0, uint32_t k1,
                                       uint32_t x0, uint32_t x1,
                                       uint32_t& o0, uint32_t& o1) {
  uint32_t ks2 = k0 ^ k1 ^ 0x1BD11BDAu;
#define TF_R(r) { x0 += x1; x1 = (x1 << (r)) | (x1 >> (32 - (r))); x1 ^= x0; }
  x0 += k0; x1 += k1;
  TF_R(13) TF_R(15) TF_R(26) TF_R(6)
  x0 += k1;  x1 += ks2 + 1u;
  TF_R(17) TF_R(29) TF_R(16) TF_R(24)
  x0 += ks2; x1 += k0 + 2u;
  TF_R(13) TF_R(15) TF_R(26) TF_R(6)
  x0 += k0;  x1 += k1 + 3u;
  TF_R(17) TF_R(29) TF_R(16) TF_R(24)
  x0 += k1;  x1 += ks2 + 4u;
  TF_R(13) TF_R(15) TF_R(26) TF_R(6)
  x0 += ks2; x1 += k0 + 5u;
#undef TF_R
  o0 = x0; o1 = x1;
}

__device__ inline float erfinv_f32(float x) {
  float w = -log1pf(-x * x);
  float p;
  if (w < 5.0f) {
    w = w - 2.5f;
    p = 2.81022636e-08f;
    p = fmaf(p, w, 3.43273939e-07f);
    p = fmaf(p, w, -3.5233877e-06f);
    p = fmaf(p, w, -4.39150654e-06f);
    p = fmaf(p, w, 0.00021858087f);
    p = fmaf(p, w, -0.00125372503f);
    p = fmaf(p, w, -0.00417768164f);
    p = fmaf(p, w, 0.246640727f);
    p = fmaf(p, w, 1.50140941f);
  } else {
    w = sqrtf(w) - 3.0f;
    p = -0.000200214257f;
    p = fmaf(p, w, 0.000100950558f);
    p = fmaf(p, w, 0.00134934322f);
    p = fmaf(p, w, -0.00367342844f);
    p = fmaf(p, w, 0.00573950773f);
    p = fmaf(p, w, -0.0076224613f);
    p = fmaf(p, w, 0.00943887047f);
    p = fmaf(p, w, 1.00167406f);
    p = fmaf(p, w, 2.83297682f);
  }
  return p * x;
}

__device__ inline float tf_normal(uint32_t k0, uint32_t k1, uint32_t i) {
  uint32_t o0, o1;
  tf2x32(k0, k1, 0u, i, o0, o1);
  uint32_t bits = o0 ^ o1;  // partitionable random_bits path
  float f = __uint_as_float(0x3F800000u | (bits >> 9)) - 1.0f;  // [0,1)
  float u = f * 2.0f + (-0.99999994f);
  u = fmaxf(-0.99999994f, u);
  return 1.41421356f * erfinv_f32(u);
}

__device__ inline unsigned short f2bf(float f) {
  uint32_t u = __float_as_uint(f);
  u += 0x7FFFu + ((u >> 16) & 1u);   // round-to-nearest-even
  return (unsigned short)(u >> 16);
}
__device__ inline float bf2f(unsigned short h) {
  return __uint_as_float(((uint32_t)h) << 16);
}

// ---------------------------------------------------------------------------
// Weight transpose + bf16 convert: Wt[n][k] = bf16(W[k][n]);  W is [K,N] fp32.
// ---------------------------------------------------------------------------
__global__ __launch_bounds__(256)
void transpose_bf16_kernel(const float* __restrict__ W,
                           unsigned short* __restrict__ Wt, int K, int N) {
  __shared__ float tile[32][33];
  int kb = blockIdx.x * 32, nb = blockIdx.y * 32;
  int tx = threadIdx.x & 31, ty = threadIdx.x >> 5;
#pragma unroll
  for (int i = 0; i < 32; i += 8)
    tile[ty + i][tx] = W[(size_t)(kb + ty + i) * N + nb + tx];
  __syncthreads();
#pragma unroll
  for (int i = 0; i < 32; i += 8)
    Wt[(size_t)(nb + ty + i) * K + kb + tx] = f2bf(tile[tx][ty + i]);
}

// ---------------------------------------------------------------------------
// Double-buffered MFMA core, 32x32x16 variant.
// Per wave: 64x64 C-tile = 2x2 of 32x32 MFMA tiles; per K=32 iter: 2 k-halves
// x 4 tiles = 8 mfma_f32_32x32x16_bf16. A/B frag: 8 contiguous bf16 at
// [row = lane&31][k = kh*16 + (lane>>5)*8]. Staging identical to r5
// (global_load_lds 16B, lane-contiguous rowx32 LDS, vmcnt(4) dbuf barriers).
// acc[tm][tn] C/D mapping (m74/m101): N-col = lane&31,
// M-row = (reg&3) + 8*(reg>>2) + 4*(lane>>5).
// ---------------------------------------------------------------------------
__device__ __forceinline__ void gemm_core_db(
    const unsigned short* __restrict__ A0, const unsigned short* __restrict__ A1,
    int lda0, int lda1, int K0, int Ktot,
    const unsigned short* __restrict__ Bt,
    int row0, int col0,
    unsigned short (*As)[128 * 32], unsigned short (*Bs)[128 * 32],
    floatx16 (&acc)[2][2]) {
  const int tid = threadIdx.x;
  const int wave = tid >> 6, lane = tid & 63;
  const int wr = wave >> 1, wc = wave & 1;
  const int lrow = lane >> 2;       // 0..15
  const int lk = (lane & 3) * 8;    // 0,8,16,24
  const int l31 = lane & 31, lhi = lane >> 5;

  auto issue = [&](int kt, int buf) {
    const int k0 = kt * 32;
    const unsigned short* Ap; int kOff, lda;
    if (k0 < K0) { Ap = A0; kOff = k0; lda = lda0; }
    else         { Ap = A1; kOff = k0 - K0; lda = lda1; }
#pragma unroll
    for (int r = 0; r < 2; r++) {
      int srow = r * 64 + wave * 16 + lrow;   // lane-contiguous LDS order
      __builtin_amdgcn_global_load_lds(
          (const __attribute__((address_space(1))) uint32_t*)
              (Ap + (size_t)(row0 + srow) * lda + kOff + lk),
          (__attribute__((address_space(3))) uint32_t*)(&As[buf][srow * 32 + lk]),
          16, 0, 0);
      __builtin_amdgcn_global_load_lds(
          (const __attribute__((address_space(1))) uint32_t*)
              (Bt + (size_t)(col0 + srow) * Ktot + k0 + lk),
          (__attribute__((address_space(3))) uint32_t*)(&Bs[buf][srow * 32 + lk]),
          16, 0, 0);
    }
  };

  const int nk = Ktot >> 5;
  issue(0, 0);
  for (int k = 0; k < nk; k++) {
    const int cur = k & 1;
    if (k + 1 < nk) {
      issue(k + 1, cur ^ 1);
      asm volatile("s_waitcnt vmcnt(4)\ns_barrier" ::: "memory");
    } else {
      asm volatile("s_waitcnt vmcnt(0)\ns_barrier" ::: "memory");
    }
    bf16x8 a[2][2], b[2][2];   // [tile][k-half]
#pragma unroll
    for (int tm = 0; tm < 2; tm++)
#pragma unroll
      for (int kh = 0; kh < 2; kh++) {
        a[tm][kh] = *(const bf16x8*)(
            &As[cur][(wr * 64 + tm * 32 + l31) * 32 + kh * 16 + lhi * 8]);
        b[tm][kh] = *(const bf16x8*)(
            &Bs[cur][(wc * 64 + tm * 32 + l31) * 32 + kh * 16 + lhi * 8]);
      }
#pragma unroll
    for (int tm = 0; tm < 2; tm++)
#pragma unroll
      for (int tn = 0; tn < 2; tn++)
#pragma unroll
        for (int kh = 0; kh < 2; kh++)
          acc[tm][tn] = __builtin_amdgcn_mfma_f32_32x32x16_bf16(
              a[tm][kh], b[tn][kh], acc[tm][tn], 0, 0, 0);
    asm volatile("s_barrier" ::: "memory");
  }
}

// XCD-aware swizzle: gy is always 64 (M=8192). by = id%64, bx = id/64 makes
// all col-blocks of one row-block share id%8 -> same XCD (performance-only).
__device__ __forceinline__ void swizzled_block(int& row0, int& col0) {
  int id = blockIdx.x + gridDim.x * blockIdx.y;
  row0 = (id & 63) << 7;
  col0 = (id >> 6) << 7;
}

// Generic GEMM. ACT: 0 none, 1 relu, 2 tanh, 3 gelu(exact),
// 4 = split: cols < nsplit -> relu+bias0 -> C0; else tanh+bias1 -> C1.
template<int ACT>
__global__ __launch_bounds__(256)
void mfma_gemm(const unsigned short* __restrict__ A0,
               const unsigned short* __restrict__ A1,
               int lda0, int lda1, int K0, int Ktot,
               const unsigned short* __restrict__ Bt,
               const float* __restrict__ bias0,
               const float* __restrict__ bias1, int nsplit,
               unsigned short* __restrict__ C0,
               unsigned short* __restrict__ C1, int ldc) {
  __shared__ unsigned short As[2][128 * 32];
  __shared__ unsigned short Bs[2][128 * 32];
  int row0, col0;
  swizzled_block(row0, col0);
  floatx16 acc[2][2];
#pragma unroll
  for (int tm = 0; tm < 2; tm++)
#pragma unroll
    for (int tn = 0; tn < 2; tn++)
#pragma unroll
      for (int r = 0; r < 16; r++) acc[tm][tn][r] = 0.f;
  gemm_core_db(A0, A1, lda0, lda1, K0, Ktot, Bt, row0, col0, As, Bs, acc);

  const int lane = threadIdx.x & 63, wave = threadIdx.x >> 6;
  const int wr = wave >> 1, wc = wave & 1;
  const int l31 = lane & 31, lhi = lane >> 5;
  const bool side = (ACT == 4) && (col0 >= nsplit);
  const float* bias = side ? bias1 : bias0;
  unsigned short* C = side ? C1 : C0;
  const int cadj = col0 - (side ? nsplit : 0) + wc * 64;
#pragma unroll
  for (int tn = 0; tn < 2; tn++) {
    int col = cadj + tn * 32 + l31;
    float bv = bias[col];
#pragma unroll
    for (int tm = 0; tm < 2; tm++) {
      int rbase = row0 + wr * 64 + tm * 32 + lhi * 4;
#pragma unroll
      for (int r = 0; r < 16; r++) {
        int row = rbase + (r & 3) + 8 * (r >> 2);
        float val = acc[tm][tn][r] + bv;
        if (ACT == 1) val = fmaxf(val, 0.0f);
        if (ACT == 2) val = tanhf(val);
        if (ACT == 3) val = 0.5f * val * (1.0f + erff(val * 0.70710678118654752f));
        if (ACT == 4) val = side ? tanhf(val) : fmaxf(val, 0.0f);
        C[(size_t)row * ldc + col] = f2bf(val);
      }
    }
  }
}

// z-batched pair of independent GEMMs (same shapes). No activation.
__global__ __launch_bounds__(256)
void mfma_gemm_pair(const unsigned short* __restrict__ Aa,
                    const unsigned short* __restrict__ Ab,
                    const unsigned short* __restrict__ Bta,
                    const unsigned short* __restrict__ Btb,
                    const float* __restrict__ biasa,
                    const float* __restrict__ biasb,
                    unsigned short* __restrict__ Ca,
                    unsigned short* __restrict__ Cb,
                    int Ktot, int ldc) {
  __shared__ unsigned short As[2][128 * 32];
  __shared__ unsigned short Bs[2][128 * 32];
  const int z = blockIdx.z;
  const unsigned short* A = z ? Ab : Aa;
  const unsigned short* Bt = z ? Btb : Bta;
  const float* bias = z ? biasb : biasa;
  unsigned short* C = z ? Cb : Ca;
  int row0, col0;
  swizzled_block(row0, col0);
  floatx16 acc[2][2];
#pragma unroll
  for (int tm = 0; tm < 2; tm++)
#pragma unroll
    for (int tn = 0; tn < 2; tn++)
#pragma unroll
      for (int r = 0; r < 16; r++) acc[tm][tn][r] = 0.f;
  gemm_core_db(A, A, Ktot, Ktot, Ktot, Ktot, Bt, row0, col0, As, Bs, acc);

  const int lane = threadIdx.x & 63, wave = threadIdx.x >> 6;
  const int wr = wave >> 1, wc = wave & 1;
  const int l31 = lane & 31, lhi = lane >> 5;
#pragma unroll
  for (int tn = 0; tn < 2; tn++) {
    int col = col0 + wc * 64 + tn * 32 + l31;
    float bv = bias[col];
#pragma unroll
    for (int tm = 0; tm < 2; tm++) {
      int rbase = row0 + wr * 64 + tm * 32 + lhi * 4;
#pragma unroll
      for (int r = 0; r < 16; r++) {
        int row = rbase + (r & 3) + 8 * (r >> 2);
        C[(size_t)row * ldc + col] = f2bf(acc[tm][tn][r] + bv);
      }
    }
  }
}

__global__ void init_normal_kernel(float* __restrict__ x,
                                   unsigned short* __restrict__ xbf,
                                   uint32_t k0, uint32_t k1, int n) {
  int i = blockIdx.x * blockDim.x + threadIdx.x;
  if (i >= n) return;
  float v = tf_normal(k0, k1, (uint32_t)i);
  x[i] = v;
  xbf[i] = f2bf(v);
}

__global__ void update_kernel(float* __restrict__ x,
                              unsigned short* __restrict__ xbf,
                              const unsigned short* __restrict__ d0,
                              const unsigned short* __restrict__ d1,
                              const unsigned short* __restrict__ itf,
                              const float* __restrict__ a_amp,
                              const float* __restrict__ b_amp,
                              const float* __restrict__ ph,
                              float coh, float c1, float sqrt_alpha,
                              float sigma, int add_noise,
                              uint32_t k0, uint32_t k1, int n) {
  int i = blockIdx.x * blockDim.x + threadIdx.x;
  if (i >= n) return;
  float aa = a_amp[0], bb = b_amp[0], pc = ph[0];
  float a2 = aa * aa, b2 = bb * bb, s = a2 + b2;
  float p0 = a2 / s, p1 = b2 / s;
  float qi = 2.0f * sqrtf(p0 * p1) * pc * coh;
  float den = sqrtf(p0) * bf2f(d0[i]) + sqrtf(p1) * bf2f(d1[i])
            + qi * bf2f(itf[i]);
  float xn = (x[i] - c1 * den) / sqrt_alpha;
  if (add_noise) {
    float nz = tf_normal(k0, k1, (uint32_t)i);
    xn += (sigma + 0.1f * fabsf(qi)) * nz;
  }
  x[i] = xn;
  xbf[i] = f2bf(xn);
}

__global__ void final_kernel(const float* __restrict__ x,
                             const float* __restrict__ real,
                             float* __restrict__ out,
                             const float* __restrict__ a_amp,
                             const float* __restrict__ b_amp,
                             uint32_t k0, uint32_t k1, int n) {
  int i = blockIdx.x * blockDim.x + threadIdx.x;
  if (i >= n) return;
  float aa = a_amp[0], bb = b_amp[0];
  float a2 = aa * aa, b2 = bb * bb;
  float p0 = a2 / (a2 + b2);
  uint32_t o0, o1;
  tf2x32(k0, k1, 0u, 0u, o0, o1);
  uint32_t bits = o0 ^ o1;
  float u = __uint_as_float(0x3F800000u | (bits >> 9)) - 1.0f;
  float xv = x[i];
  out[i] = (u < p0) ? (0.7f * xv + 0.3f * real[i]) : xv;
}

extern "C" void kernel_launch(void* const* d_in, const int* in_sizes, int n_in,
                              void* d_out, int out_size, void* d_ws,
                              size_t ws_size, hipStream_t stream) {
  const float* real = (const float*)d_in[0];
  const float* Wq  = (const float*)d_in[2];
  const float* bq  = (const float*)d_in[3];
  const float* W01 = (const float*)d_in[4];
  const float* b01 = (const float*)d_in[5];
  const float* W02 = (const float*)d_in[6];
  const float* b02 = (const float*)d_in[7];
  const float* W11 = (const float*)d_in[8];
  const float* b11 = (const float*)d_in[9];
  const float* W12 = (const float*)d_in[10];
  const float* b12 = (const float*)d_in[11];
  const float* Wi1 = (const float*)d_in[12];
  const float* bi1 = (const float*)d_in[13];
  const float* Wi2 = (const float*)d_in[14];
  const float* bi2 = (const float*)d_in[15];
  const float* a_amp = (const float*)d_in[16];
  const float* b_amp = (const float*)d_in[17];
  const float* ph    = (const float*)d_in[18];

  const int Nn = 8192, F = 512, H = 1024;
  const int nElem = Nn * F;  // 4,194,304
  const int NSPLIT_OFF = 1 << 30;

  // workspace layout
  char* ws = (char*)d_ws;
  float* x = (float*)ws;                                   ws += (size_t)nElem * 4;
  unsigned short* xbf = (unsigned short*)ws;               ws += (size_t)nElem * 2;
  unsigned short* qf  = (unsigned short*)ws;               ws += (size_t)Nn * H * 2;
  unsigned short* h0  = (unsigned short*)ws;               ws += (size_t)Nn * H * 2;
  unsigned short* h1  = (unsigned short*)ws;               ws += (size_t)Nn * H * 2;
  unsigned short* d0  = (unsigned short*)ws;               ws += (size_t)nElem * 2;
  unsigned short* d1  = (unsigned short*)ws;               ws += (size_t)nElem * 2;
  unsigned short* itf = (unsigned short*)ws;               ws += (size_t)nElem * 2;
  unsigned short* Wq_t  = (unsigned short*)ws;             ws += (size_t)F * H * 2;
  unsigned short* WA_t  = (unsigned short*)ws;             ws += (size_t)(2 * H) * H * 2; // [W01_t ; W11_t]
  unsigned short* W02_t = (unsigned short*)ws;             ws += (size_t)H * F * 2;
  unsigned short* W12_t = (unsigned short*)ws;             ws += (size_t)H * F * 2;
  unsigned short* Wi1_t = (unsigned short*)ws;             ws += (size_t)(2 * F) * H * 2;
  unsigned short* Wi2_t = (unsigned short*)ws;             ws += (size_t)H * F * 2;

  dim3 tb(256);
  transpose_bf16_kernel<<<dim3(F / 32, H / 32), tb, 0, stream>>>(Wq, Wq_t, F, H);
  transpose_bf16_kernel<<<dim3(H / 32, H / 32), tb, 0, stream>>>(W01, WA_t, H, H);
  transpose_bf16_kernel<<<dim3(H / 32, H / 32), tb, 0, stream>>>(W11, WA_t + (size_t)H * H, H, H);
  transpose_bf16_kernel<<<dim3(H / 32, F / 32), tb, 0, stream>>>(W02, W02_t, H, F);
  transpose_bf16_kernel<<<dim3(H / 32, F / 32), tb, 0, stream>>>(W12, W12_t, H, F);
  transpose_bf16_kernel<<<dim3(2 * F / 32, H / 32), tb, 0, stream>>>(Wi1, Wi1_t, 2 * F, H);
  transpose_bf16_kernel<<<dim3(H / 32, F / 32), tb, 0, stream>>>(Wi2, Wi2_t, H, F);

  uint32_t kx0, kx1; tf2x32(0u, 1u, 0u, 10000u, kx0, kx1);
  init_normal_kernel<<<(nElem + 255) / 256, 256, 0, stream>>>(x, xbf, kx0, kx1, nElem);

  float sched[100];
  for (int i = 0; i < 100; i++)
    sched[i] = (float)(1e-4 + (0.02 - 1e-4) * (double)i / 99.0);
  const float decay = expf(-0.1f);
  float coh = 1.0f;

  dim3 blk(256);
  dim3 g1(H / 128, 64);            // 512 blocks
  dim3 g2(2 * H / 128, 64);        // 1024 blocks
  dim3 g45(F / 128, 64, 2);        // 512 blocks
  dim3 g6(H / 128, 64);            // 512 blocks
  dim3 g7(F / 128, 64);            // 256 blocks

  for (int j = 0; j < 50; j++) {
    int t = 49 - j;
    // G1: qf = relu(x @ Wq + bq)
    mfma_gemm<1><<<g1, blk, 0, stream>>>(xbf, xbf, F, F, F, F, Wq_t,
                                         bq, nullptr, NSPLIT_OFF, qf, nullptr, H);
    // G2 merged: h0 = relu(qf@W01+b01), h1 = tanh(qf@W11+b11), N=2048 GEMM
    mfma_gemm<4><<<g2, blk, 0, stream>>>(qf, qf, H, H, H, H, WA_t,
                                         b01, b11, H, h0, h1, H);
    // G4/G5 z-batched: d0 = h0@W02+b02 ; d1 = h1@W12+b12
    mfma_gemm_pair<<<g45, blk, 0, stream>>>(h0, h1, W02_t, W12_t, b02, b12,
                                            d0, d1, H, F);
    // G6: qf(reused) = gelu([d0|d1] @ Wi1 + bi1)
    mfma_gemm<3><<<g6, blk, 0, stream>>>(d0, d1, F, F, F, 2 * F, Wi1_t,
                                         bi1, nullptr, NSPLIT_OFF, qf, nullptr, H);
    // G7: itf = qf @ Wi2 + bi2
    mfma_gemm<0><<<g7, blk, 0, stream>>>(qf, qf, H, H, H, H, Wi2_t,
                                         bi2, nullptr, NSPLIT_OFF, itf, nullptr, F);

    float schedt = sched[t];
    float alphaf = fmaxf(1.0f - schedt, 1e-8f);
    float one_m_alpha = 1.0f - alphaf;
    float sqrt_1ma = sqrtf(fmaxf(one_m_alpha, 1e-8f));
    float c1 = one_m_alpha / sqrt_1ma;
    float sqa = sqrtf(alphaf);
    float sigma = 0.0f;
    if (t > 0) {
      float ap = 1.0f - sched[t - 1];
      sigma = sqrtf(fmaxf((1.0f - ap) / one_m_alpha * (1.0f - alphaf / ap), 0.0f));
    }
    uint32_t kt0, kt1; tf2x32(0u, 1u, 0u, (uint32_t)t, kt0, kt1);
    update_kernel<<<(nElem + 255) / 256, 256, 0, stream>>>(
        x, xbf, d0, d1, itf, a_amp, b_amp, ph, coh, c1, sqa, sigma,
        (t > 0) ? 1 : 0, kt0, kt1, nElem);
    coh *= decay;
  }

  uint32_t ku0, ku1; tf2x32(0u, 1u, 0u, 99999u, ku0, ku1);
  final_kernel<<<(nElem + 255) / 256, 256, 0, stream>>>(
      x, real, (float*)d_out, a_amp, b_amp, ku0, ku1, nElem);
}

// Round 9
// 8881.245 us; speedup vs baseline: 1.7293x; 1.1430x over previous
//
#include <hip/hip_runtime.h>
#include <stdint.h>
#include <math.h>

// ---------------------------------------------------------------------------
// QuantumDiffusionDreamer — round 9: r5 structure/tiling (measured best
// 9.42 ms) with 512-thread blocks: same 128x128 tile, 8 waves, each wave a
// 32x64 sub-tile (acc 2x4 of 16x16x32). Doubles waves/SIMD (2->4) at the
// same grid to hide the K-loop barrier drain (m114 co-residency). Identical
// MFMA order -> bit-identical output to r5. Staging: 2 global_load_lds(16B)
// per thread, dbuf with raw `s_waitcnt vmcnt(2); s_barrier`.
// r8 lesson kept: 16x16 fragment reads are LDS-bank-balanced; 32x32 is not.
// PRNG: JAX threefry2x32 partitionable (verified r1-r8). x stays fp32.
// ---------------------------------------------------------------------------

typedef __bf16 bf16x8 __attribute__((ext_vector_type(8)));
typedef float floatx4 __attribute__((ext_vector_type(4)));

__host__ __device__ inline void tf2x32(uint32_t k0, uint32_t k1,
                                       uint32_t x0, uint32_t x1,
                                       uint32_t& o0, uint32_t& o1) {
  uint32_t ks2 = k0 ^ k1 ^ 0x1BD11BDAu;
#define TF_R(r) { x0 += x1; x1 = (x1 << (r)) | (x1 >> (32 - (r))); x1 ^= x0; }
  x0 += k0; x1 += k1;
  TF_R(13) TF_R(15) TF_R(26) TF_R(6)
  x0 += k1;  x1 += ks2 + 1u;
  TF_R(17) TF_R(29) TF_R(16) TF_R(24)
  x0 += ks2; x1 += k0 + 2u;
  TF_R(13) TF_R(15) TF_R(26) TF_R(6)
  x0 += k0;  x1 += k1 + 3u;
  TF_R(17) TF_R(29) TF_R(16) TF_R(24)
  x0 += k1;  x1 += ks2 + 4u;
  TF_R(13) TF_R(15) TF_R(26) TF_R(6)
  x0 += ks2; x1 += k0 + 5u;
#undef TF_R
  o0 = x0; o1 = x1;
}

__device__ inline float erfinv_f32(float x) {
  float w = -log1pf(-x * x);
  float p;
  if (w < 5.0f) {
    w = w - 2.5f;
    p = 2.81022636e-08f;
    p = fmaf(p, w, 3.43273939e-07f);
    p = fmaf(p, w, -3.5233877e-06f);
    p = fmaf(p, w, -4.39150654e-06f);
    p = fmaf(p, w, 0.00021858087f);
    p = fmaf(p, w, -0.00125372503f);
    p = fmaf(p, w, -0.00417768164f);
    p = fmaf(p, w, 0.246640727f);
    p = fmaf(p, w, 1.50140941f);
  } else {
    w = sqrtf(w) - 3.0f;
    p = -0.000200214257f;
    p = fmaf(p, w, 0.000100950558f);
    p = fmaf(p, w, 0.00134934322f);
    p = fmaf(p, w, -0.00367342844f);
    p = fmaf(p, w, 0.00573950773f);
    p = fmaf(p, w, -0.0076224613f);
    p = fmaf(p, w, 0.00943887047f);
    p = fmaf(p, w, 1.00167406f);
    p = fmaf(p, w, 2.83297682f);
  }
  return p * x;
}

__device__ inline float tf_normal(uint32_t k0, uint32_t k1, uint32_t i) {
  uint32_t o0, o1;
  tf2x32(k0, k1, 0u, i, o0, o1);
  uint32_t bits = o0 ^ o1;  // partitionable random_bits path
  float f = __uint_as_float(0x3F800000u | (bits >> 9)) - 1.0f;  // [0,1)
  float u = f * 2.0f + (-0.99999994f);
  u = fmaxf(-0.99999994f, u);
  return 1.41421356f * erfinv_f32(u);
}

__device__ inline unsigned short f2bf(float f) {
  uint32_t u = __float_as_uint(f);
  u += 0x7FFFu + ((u >> 16) & 1u);   // round-to-nearest-even
  return (unsigned short)(u >> 16);
}
__device__ inline float bf2f(unsigned short h) {
  return __uint_as_float(((uint32_t)h) << 16);
}

// ---------------------------------------------------------------------------
// Weight transpose + bf16 convert: Wt[n][k] = bf16(W[k][n]);  W is [K,N] fp32.
// ---------------------------------------------------------------------------
__global__ __launch_bounds__(256)
void transpose_bf16_kernel(const float* __restrict__ W,
                           unsigned short* __restrict__ Wt, int K, int N) {
  __shared__ float tile[32][33];
  int kb = blockIdx.x * 32, nb = blockIdx.y * 32;
  int tx = threadIdx.x & 31, ty = threadIdx.x >> 5;
#pragma unroll
  for (int i = 0; i < 32; i += 8)
    tile[ty + i][tx] = W[(size_t)(kb + ty + i) * N + nb + tx];
  __syncthreads();
#pragma unroll
  for (int i = 0; i < 32; i += 8)
    Wt[(size_t)(nb + ty + i) * K + kb + tx] = f2bf(tile[tx][ty + i]);
}

// ---------------------------------------------------------------------------
// Double-buffered MFMA core, 512 threads (8 waves). Wave w computes the
// 32x64 sub-tile rows [(w>>1)*32,+32) x cols [(w&1)*64,+64) of the 128x128
// block tile: acc[2][4] of 16x16x32 bf16 MFMA. Frag reads use the
// bank-balanced 16x16 pattern (fm*64 + quad*16 B). Staging: thread t loads
// A granule t and B granule t (16 B each); LDS dest = t*16 B (wave-uniform
// base + lane*16 ✓). K-tile BK=32; `s_waitcnt vmcnt(2); s_barrier` dbuf.
// ---------------------------------------------------------------------------
__device__ __forceinline__ void gemm_core_db(
    const unsigned short* __restrict__ A0, const unsigned short* __restrict__ A1,
    int lda0, int lda1, int K0, int Ktot,
    const unsigned short* __restrict__ Bt,
    int row0, int col0,
    unsigned short (*As)[128 * 32], unsigned short (*Bs)[128 * 32],
    floatx4 (&acc)[2][4]) {
  const int tid = threadIdx.x;            // 0..511
  const int wave = tid >> 6, lane = tid & 63;
  const int wr = wave >> 1, wc = wave & 1;  // 32-row band / 64-col band
  const int srow = tid >> 2;              // 0..127 (staging row)
  const int sgr = (tid & 3) * 8;          // staging granule offset (shorts)
  const int fm = lane & 15, quad = lane >> 4;

  auto issue = [&](int kt, int buf) {
    const int k0 = kt * 32;
    const unsigned short* Ap; int kOff, lda;
    if (k0 < K0) { Ap = A0; kOff = k0; lda = lda0; }
    else         { Ap = A1; kOff = k0 - K0; lda = lda1; }
    __builtin_amdgcn_global_load_lds(
        (const __attribute__((address_space(1))) uint32_t*)
            (Ap + (size_t)(row0 + srow) * lda + kOff + sgr),
        (__attribute__((address_space(3))) uint32_t*)(&As[buf][srow * 32 + sgr]),
        16, 0, 0);
    __builtin_amdgcn_global_load_lds(
        (const __attribute__((address_space(1))) uint32_t*)
            (Bt + (size_t)(col0 + srow) * Ktot + k0 + sgr),
        (__attribute__((address_space(3))) uint32_t*)(&Bs[buf][srow * 32 + sgr]),
        16, 0, 0);
  };

  const int nk = Ktot >> 5;
  issue(0, 0);
  for (int k = 0; k < nk; k++) {
    const int cur = k & 1;
    if (k + 1 < nk) {
      issue(k + 1, cur ^ 1);
      asm volatile("s_waitcnt vmcnt(2)\ns_barrier" ::: "memory");
    } else {
      asm volatile("s_waitcnt vmcnt(0)\ns_barrier" ::: "memory");
    }
    bf16x8 a[2], b[4];
#pragma unroll
    for (int tm = 0; tm < 2; tm++)
      a[tm] = *(const bf16x8*)(&As[cur][(wr * 32 + tm * 16 + fm) * 32 + quad * 8]);
#pragma unroll
    for (int tn = 0; tn < 4; tn++)
      b[tn] = *(const bf16x8*)(&Bs[cur][(wc * 64 + tn * 16 + fm) * 32 + quad * 8]);
#pragma unroll
    for (int tm = 0; tm < 2; tm++)
#pragma unroll
      for (int tn = 0; tn < 4; tn++)
        acc[tm][tn] = __builtin_amdgcn_mfma_f32_16x16x32_bf16(a[tm], b[tn],
                                                              acc[tm][tn], 0, 0, 0);
    asm volatile("s_barrier" ::: "memory");
  }
}

// XCD-aware swizzle: gy is always 64 (M=8192). by = id%64, bx = id/64 makes
// all col-blocks of one row-block share id%8 -> same XCD (performance-only).
__device__ __forceinline__ void swizzled_block(int& row0, int& col0) {
  int id = blockIdx.x + gridDim.x * blockIdx.y;
  row0 = (id & 63) << 7;
  col0 = (id >> 6) << 7;
}

// Generic GEMM. ACT: 0 none, 1 relu, 2 tanh, 3 gelu(exact),
// 4 = split: cols < nsplit -> relu+bias0 -> C0; else tanh+bias1 -> C1.
template<int ACT>
__global__ __launch_bounds__(512, 4)
void mfma_gemm(const unsigned short* __restrict__ A0,
               const unsigned short* __restrict__ A1,
               int lda0, int lda1, int K0, int Ktot,
               const unsigned short* __restrict__ Bt,
               const float* __restrict__ bias0,
               const float* __restrict__ bias1, int nsplit,
               unsigned short* __restrict__ C0,
               unsigned short* __restrict__ C1, int ldc) {
  __shared__ unsigned short As[2][128 * 32];
  __shared__ unsigned short Bs[2][128 * 32];
  int row0, col0;
  swizzled_block(row0, col0);
  floatx4 acc[2][4];
#pragma unroll
  for (int tm = 0; tm < 2; tm++)
#pragma unroll
    for (int tn = 0; tn < 4; tn++) acc[tm][tn] = (floatx4){0.f, 0.f, 0.f, 0.f};
  gemm_core_db(A0, A1, lda0, lda1, K0, Ktot, Bt, row0, col0, As, Bs, acc);

  const int lane = threadIdx.x & 63, wave = threadIdx.x >> 6;
  const int wr = wave >> 1, wc = wave & 1;
  const int fm = lane & 15, quad = lane >> 4;
  const bool side = (ACT == 4) && (col0 >= nsplit);
  const float* bias = side ? bias1 : bias0;
  unsigned short* C = side ? C1 : C0;
  const int cbase = col0 - (side ? nsplit : 0);
#pragma unroll
  for (int tn = 0; tn < 4; tn++) {
    int col = cbase + wc * 64 + tn * 16 + fm;
    float bv = bias[col];
#pragma unroll
    for (int tm = 0; tm < 2; tm++) {
      int rbase = row0 + wr * 32 + tm * 16 + quad * 4;
#pragma unroll
      for (int r = 0; r < 4; r++) {
        float val = acc[tm][tn][r] + bv;
        if (ACT == 1) val = fmaxf(val, 0.0f);
        if (ACT == 2) val = tanhf(val);
        if (ACT == 3) val = 0.5f * val * (1.0f + erff(val * 0.70710678118654752f));
        if (ACT == 4) val = side ? tanhf(val) : fmaxf(val, 0.0f);
        C[(size_t)(rbase + r) * ldc + col] = f2bf(val);
      }
    }
  }
}

// z-batched pair of independent GEMMs (same shapes). No activation.
__global__ __launch_bounds__(512, 4)
void mfma_gemm_pair(const unsigned short* __restrict__ Aa,
                    const unsigned short* __restrict__ Ab,
                    const unsigned short* __restrict__ Bta,
                    const unsigned short* __restrict__ Btb,
                    const float* __restrict__ biasa,
                    const float* __restrict__ biasb,
                    unsigned short* __restrict__ Ca,
                    unsigned short* __restrict__ Cb,
                    int Ktot, int ldc) {
  __shared__ unsigned short As[2][128 * 32];
  __shared__ unsigned short Bs[2][128 * 32];
  const int z = blockIdx.z;
  const unsigned short* A = z ? Ab : Aa;
  const unsigned short* Bt = z ? Btb : Bta;
  const float* bias = z ? biasb : biasa;
  unsigned short* C = z ? Cb : Ca;
  int row0, col0;
  swizzled_block(row0, col0);
  floatx4 acc[2][4];
#pragma unroll
  for (int tm = 0; tm < 2; tm++)
#pragma unroll
    for (int tn = 0; tn < 4; tn++) acc[tm][tn] = (floatx4){0.f, 0.f, 0.f, 0.f};
  gemm_core_db(A, A, Ktot, Ktot, Ktot, Ktot, Bt, row0, col0, As, Bs, acc);

  const int lane = threadIdx.x & 63, wave = threadIdx.x >> 6;
  const int wr = wave >> 1, wc = wave & 1;
  const int fm = lane & 15, quad = lane >> 4;
#pragma unroll
  for (int tn = 0; tn < 4; tn++) {
    int col = col0 + wc * 64 + tn * 16 + fm;
    float bv = bias[col];
#pragma unroll
    for (int tm = 0; tm < 2; tm++) {
      int rbase = row0 + wr * 32 + tm * 16 + quad * 4;
#pragma unroll
      for (int r = 0; r < 4; r++)
        C[(size_t)(rbase + r) * ldc + col] = f2bf(acc[tm][tn][r] + bv);
    }
  }
}

__global__ void init_normal_kernel(float* __restrict__ x,
                                   unsigned short* __restrict__ xbf,
                                   uint32_t k0, uint32_t k1, int n) {
  int i = blockIdx.x * blockDim.x + threadIdx.x;
  if (i >= n) return;
  float v = tf_normal(k0, k1, (uint32_t)i);
  x[i] = v;
  xbf[i] = f2bf(v);
}

__global__ void update_kernel(float* __restrict__ x,
                              unsigned short* __restrict__ xbf,
                              const unsigned short* __restrict__ d0,
                              const unsigned short* __restrict__ d1,
                              const unsigned short* __restrict__ itf,
                              const float* __restrict__ a_amp,
                              const float* __restrict__ b_amp,
                              const float* __restrict__ ph,
                              float coh, float c1, float sqrt_alpha,
                              float sigma, int add_noise,
                              uint32_t k0, uint32_t k1, int n) {
  int i = blockIdx.x * blockDim.x + threadIdx.x;
  if (i >= n) return;
  float aa = a_amp[0], bb = b_amp[0], pc = ph[0];
  float a2 = aa * aa, b2 = bb * bb, s = a2 + b2;
  float p0 = a2 / s, p1 = b2 / s;
  float qi = 2.0f * sqrtf(p0 * p1) * pc * coh;
  float den = sqrtf(p0) * bf2f(d0[i]) + sqrtf(p1) * bf2f(d1[i])
            + qi * bf2f(itf[i]);
  float xn = (x[i] - c1 * den) / sqrt_alpha;
  if (add_noise) {
    float nz = tf_normal(k0, k1, (uint32_t)i);
    xn += (sigma + 0.1f * fabsf(qi)) * nz;
  }
  x[i] = xn;
  xbf[i] = f2bf(xn);
}

__global__ void final_kernel(const float* __restrict__ x,
                             const float* __restrict__ real,
                             float* __restrict__ out,
                             const float* __restrict__ a_amp,
                             const float* __restrict__ b_amp,
                             uint32_t k0, uint32_t k1, int n) {
  int i = blockIdx.x * blockDim.x + threadIdx.x;
  if (i >= n) return;
  float aa = a_amp[0], bb = b_amp[0];
  float a2 = aa * aa, b2 = bb * bb;
  float p0 = a2 / (a2 + b2);
  uint32_t o0, o1;
  tf2x32(k0, k1, 0u, 0u, o0, o1);
  uint32_t bits = o0 ^ o1;
  float u = __uint_as_float(0x3F800000u | (bits >> 9)) - 1.0f;
  float xv = x[i];
  out[i] = (u < p0) ? (0.7f * xv + 0.3f * real[i]) : xv;
}

extern "C" void kernel_launch(void* const* d_in, const int* in_sizes, int n_in,
                              void* d_out, int out_size, void* d_ws,
                              size_t ws_size, hipStream_t stream) {
  const float* real = (const float*)d_in[0];
  const float* Wq  = (const float*)d_in[2];
  const float* bq  = (const float*)d_in[3];
  const float* W01 = (const float*)d_in[4];
  const float* b01 = (const float*)d_in[5];
  const float* W02 = (const float*)d_in[6];
  const float* b02 = (const float*)d_in[7];
  const float* W11 = (const float*)d_in[8];
  const float* b11 = (const float*)d_in[9];
  const float* W12 = (const float*)d_in[10];
  const float* b12 = (const float*)d_in[11];
  const float* Wi1 = (const float*)d_in[12];
  const float* bi1 = (const float*)d_in[13];
  const float* Wi2 = (const float*)d_in[14];
  const float* bi2 = (const float*)d_in[15];
  const float* a_amp = (const float*)d_in[16];
  const float* b_amp = (const float*)d_in[17];
  const float* ph    = (const float*)d_in[18];

  const int Nn = 8192, F = 512, H = 1024;
  const int nElem = Nn * F;  // 4,194,304
  const int NSPLIT_OFF = 1 << 30;

  // workspace layout
  char* ws = (char*)d_ws;
  float* x = (float*)ws;                                   ws += (size_t)nElem * 4;
  unsigned short* xbf = (unsigned short*)ws;               ws += (size_t)nElem * 2;
  unsigned short* qf  = (unsigned short*)ws;               ws += (size_t)Nn * H * 2;
  unsigned short* h0  = (unsigned short*)ws;               ws += (size_t)Nn * H * 2;
  unsigned short* h1  = (unsigned short*)ws;               ws += (size_t)Nn * H * 2;
  unsigned short* d0  = (unsigned short*)ws;               ws += (size_t)nElem * 2;
  unsigned short* d1  = (unsigned short*)ws;               ws += (size_t)nElem * 2;
  unsigned short* itf = (unsigned short*)ws;               ws += (size_t)nElem * 2;
  unsigned short* Wq_t  = (unsigned short*)ws;             ws += (size_t)F * H * 2;
  unsigned short* WA_t  = (unsigned short*)ws;             ws += (size_t)(2 * H) * H * 2; // [W01_t ; W11_t]
  unsigned short* W02_t = (unsigned short*)ws;             ws += (size_t)H * F * 2;
  unsigned short* W12_t = (unsigned short*)ws;             ws += (size_t)H * F * 2;
  unsigned short* Wi1_t = (unsigned short*)ws;             ws += (size_t)(2 * F) * H * 2;
  unsigned short* Wi2_t = (unsigned short*)ws;             ws += (size_t)H * F * 2;

  dim3 tb(256);
  transpose_bf16_kernel<<<dim3(F / 32, H / 32), tb, 0, stream>>>(Wq, Wq_t, F, H);
  transpose_bf16_kernel<<<dim3(H / 32, H / 32), tb, 0, stream>>>(W01, WA_t, H, H);
  transpose_bf16_kernel<<<dim3(H / 32, H / 32), tb, 0, stream>>>(W11, WA_t + (size_t)H * H, H, H);
  transpose_bf16_kernel<<<dim3(H / 32, F / 32), tb, 0, stream>>>(W02, W02_t, H, F);
  transpose_bf16_kernel<<<dim3(H / 32, F / 32), tb, 0, stream>>>(W12, W12_t, H, F);
  transpose_bf16_kernel<<<dim3(2 * F / 32, H / 32), tb, 0, stream>>>(Wi1, Wi1_t, 2 * F, H);
  transpose_bf16_kernel<<<dim3(H / 32, F / 32), tb, 0, stream>>>(Wi2, Wi2_t, H, F);

  uint32_t kx0, kx1; tf2x32(0u, 1u, 0u, 10000u, kx0, kx1);
  init_normal_kernel<<<(nElem + 255) / 256, 256, 0, stream>>>(x, xbf, kx0, kx1, nElem);

  float sched[100];
  for (int i = 0; i < 100; i++)
    sched[i] = (float)(1e-4 + (0.02 - 1e-4) * (double)i / 99.0);
  const float decay = expf(-0.1f);
  float coh = 1.0f;

  dim3 blk(512);
  dim3 g1(H / 128, 64);            // 512 blocks
  dim3 g2(2 * H / 128, 64);        // 1024 blocks
  dim3 g45(F / 128, 64, 2);        // 512 blocks
  dim3 g6(H / 128, 64);            // 512 blocks
  dim3 g7(F / 128, 64);            // 256 blocks

  for (int j = 0; j < 50; j++) {
    int t = 49 - j;
    // G1: qf = relu(x @ Wq + bq)
    mfma_gemm<1><<<g1, blk, 0, stream>>>(xbf, xbf, F, F, F, F, Wq_t,
                                         bq, nullptr, NSPLIT_OFF, qf, nullptr, H);
    // G2 merged: h0 = relu(qf@W01+b01), h1 = tanh(qf@W11+b11), N=2048 GEMM
    mfma_gemm<4><<<g2, blk, 0, stream>>>(qf, qf, H, H, H, H, WA_t,
                                         b01, b11, H, h0, h1, H);
    // G4/G5 z-batched: d0 = h0@W02+b02 ; d1 = h1@W12+b12
    mfma_gemm_pair<<<g45, blk, 0, stream>>>(h0, h1, W02_t, W12_t, b02, b12,
                                            d0, d1, H, F);
    // G6: qf(reused) = gelu([d0|d1] @ Wi1 + bi1)
    mfma_gemm<3><<<g6, blk, 0, stream>>>(d0, d1, F, F, F, 2 * F, Wi1_t,
                                         bi1, nullptr, NSPLIT_OFF, qf, nullptr, H);
    // G7: itf = qf @ Wi2 + bi2
    mfma_gemm<0><<<g7, blk, 0, stream>>>(qf, qf, H, H, H, H, Wi2_t,
                                         bi2, nullptr, NSPLIT_OFF, itf, nullptr, F);

    float schedt = sched[t];
    float alphaf = fmaxf(1.0f - schedt, 1e-8f);
    float one_m_alpha = 1.0f - alphaf;
    float sqrt_1ma = sqrtf(fmaxf(one_m_alpha, 1e-8f));
    float c1 = one_m_alpha / sqrt_1ma;
    float sqa = sqrtf(alphaf);
    float sigma = 0.0f;
    if (t > 0) {
      float ap = 1.0f - sched[t - 1];
      sigma = sqrtf(fmaxf((1.0f - ap) / one_m_alpha * (1.0f - alphaf / ap), 0.0f));
    }
    uint32_t kt0, kt1; tf2x32(0u, 1u, 0u, (uint32_t)t, kt0, kt1);
    update_kernel<<<(nElem + 255) / 256, 256, 0, stream>>>(
        x, xbf, d0, d1, itf, a_amp, b_amp, ph, coh, c1, sqa, sigma,
        (t > 0) ? 1 : 0, kt0, kt1, nElem);
    coh *= decay;
  }

  uint32_t ku0, ku1; tf2x32(0u, 1u, 0u, 99999u, ku0, ku1);
  final_kernel<<<(nElem + 255) / 256, 256, 0, stream>>>(
      x, real, (float*)d_out, a_amp, b_amp, ku0, ku1, nElem);
}

// Round 10
// 8392.229 us; speedup vs baseline: 1.8301x; 1.0583x over previous
//
#include <hip/hip_runtime.h>
#include <stdint.h>
#include <math.h>

// ---------------------------------------------------------------------------
// QuantumDiffusionDreamer — round 10: r9 (measured best 8.88 ms) + G7
// restructured: 64x128 tile (512 blocks, 512 threads) with the DDPM update
// fused into the epilogue. Fixes G7's 1-block/CU starvation AND removes the
// itf materialization + standalone update dispatch.
// r7 lesson respected: PRNG in epilogue only at high occupancy (16 waves/CU,
// 16 normals/thread here vs r7's 4 waves/CU, 64/thread).
// r8 lesson kept: 16x16 fragment reads (row stride 64 B) are bank-balanced.
// PRNG: JAX threefry2x32 partitionable (verified r1-r9). x stays fp32.
// ---------------------------------------------------------------------------

typedef __bf16 bf16x8 __attribute__((ext_vector_type(8)));
typedef float floatx4 __attribute__((ext_vector_type(4)));

__host__ __device__ inline void tf2x32(uint32_t k0, uint32_t k1,
                                       uint32_t x0, uint32_t x1,
                                       uint32_t& o0, uint32_t& o1) {
  uint32_t ks2 = k0 ^ k1 ^ 0x1BD11BDAu;
#define TF_R(r) { x0 += x1; x1 = (x1 << (r)) | (x1 >> (32 - (r))); x1 ^= x0; }
  x0 += k0; x1 += k1;
  TF_R(13) TF_R(15) TF_R(26) TF_R(6)
  x0 += k1;  x1 += ks2 + 1u;
  TF_R(17) TF_R(29) TF_R(16) TF_R(24)
  x0 += ks2; x1 += k0 + 2u;
  TF_R(13) TF_R(15) TF_R(26) TF_R(6)
  x0 += k0;  x1 += k1 + 3u;
  TF_R(17) TF_R(29) TF_R(16) TF_R(24)
  x0 += k1;  x1 += ks2 + 4u;
  TF_R(13) TF_R(15) TF_R(26) TF_R(6)
  x0 += ks2; x1 += k0 + 5u;
#undef TF_R
  o0 = x0; o1 = x1;
}

__device__ inline float erfinv_f32(float x) {
  float w = -log1pf(-x * x);
  float p;
  if (w < 5.0f) {
    w = w - 2.5f;
    p = 2.81022636e-08f;
    p = fmaf(p, w, 3.43273939e-07f);
    p = fmaf(p, w, -3.5233877e-06f);
    p = fmaf(p, w, -4.39150654e-06f);
    p = fmaf(p, w, 0.00021858087f);
    p = fmaf(p, w, -0.00125372503f);
    p = fmaf(p, w, -0.00417768164f);
    p = fmaf(p, w, 0.246640727f);
    p = fmaf(p, w, 1.50140941f);
  } else {
    w = sqrtf(w) - 3.0f;
    p = -0.000200214257f;
    p = fmaf(p, w, 0.000100950558f);
    p = fmaf(p, w, 0.00134934322f);
    p = fmaf(p, w, -0.00367342844f);
    p = fmaf(p, w, 0.00573950773f);
    p = fmaf(p, w, -0.0076224613f);
    p = fmaf(p, w, 0.00943887047f);
    p = fmaf(p, w, 1.00167406f);
    p = fmaf(p, w, 2.83297682f);
  }
  return p * x;
}

__device__ inline float tf_normal(uint32_t k0, uint32_t k1, uint32_t i) {
  uint32_t o0, o1;
  tf2x32(k0, k1, 0u, i, o0, o1);
  uint32_t bits = o0 ^ o1;  // partitionable random_bits path
  float f = __uint_as_float(0x3F800000u | (bits >> 9)) - 1.0f;  // [0,1)
  float u = f * 2.0f + (-0.99999994f);
  u = fmaxf(-0.99999994f, u);
  return 1.41421356f * erfinv_f32(u);
}

__device__ inline unsigned short f2bf(float f) {
  uint32_t u = __float_as_uint(f);
  u += 0x7FFFu + ((u >> 16) & 1u);   // round-to-nearest-even
  return (unsigned short)(u >> 16);
}
__device__ inline float bf2f(unsigned short h) {
  return __uint_as_float(((uint32_t)h) << 16);
}

// ---------------------------------------------------------------------------
// Weight transpose + bf16 convert: Wt[n][k] = bf16(W[k][n]);  W is [K,N] fp32.
// ---------------------------------------------------------------------------
__global__ __launch_bounds__(256)
void transpose_bf16_kernel(const float* __restrict__ W,
                           unsigned short* __restrict__ Wt, int K, int N) {
  __shared__ float tile[32][33];
  int kb = blockIdx.x * 32, nb = blockIdx.y * 32;
  int tx = threadIdx.x & 31, ty = threadIdx.x >> 5;
#pragma unroll
  for (int i = 0; i < 32; i += 8)
    tile[ty + i][tx] = W[(size_t)(kb + ty + i) * N + nb + tx];
  __syncthreads();
#pragma unroll
  for (int i = 0; i < 32; i += 8)
    Wt[(size_t)(nb + ty + i) * K + kb + tx] = f2bf(tile[tx][ty + i]);
}

// ---------------------------------------------------------------------------
// Double-buffered MFMA core, 512 threads (8 waves), 128x128 tile (r9 core).
// Wave w: 32x64 sub-tile; acc[2][4] of 16x16x32. Bank-balanced frag reads.
// Staging: thread t loads A granule t + B granule t (16 B each), LDS dest
// t*16 B (wave-uniform base + lane*16). `s_waitcnt vmcnt(2); s_barrier` dbuf.
// ---------------------------------------------------------------------------
__device__ __forceinline__ void gemm_core_db(
    const unsigned short* __restrict__ A0, const unsigned short* __restrict__ A1,
    int lda0, int lda1, int K0, int Ktot,
    const unsigned short* __restrict__ Bt,
    int row0, int col0,
    unsigned short (*As)[128 * 32], unsigned short (*Bs)[128 * 32],
    floatx4 (&acc)[2][4]) {
  const int tid = threadIdx.x;            // 0..511
  const int wave = tid >> 6, lane = tid & 63;
  const int wr = wave >> 1, wc = wave & 1;  // 32-row band / 64-col band
  const int srow = tid >> 2;              // 0..127 (staging row)
  const int sgr = (tid & 3) * 8;          // staging granule offset (shorts)
  const int fm = lane & 15, quad = lane >> 4;

  auto issue = [&](int kt, int buf) {
    const int k0 = kt * 32;
    const unsigned short* Ap; int kOff, lda;
    if (k0 < K0) { Ap = A0; kOff = k0; lda = lda0; }
    else         { Ap = A1; kOff = k0 - K0; lda = lda1; }
    __builtin_amdgcn_global_load_lds(
        (const __attribute__((address_space(1))) uint32_t*)
            (Ap + (size_t)(row0 + srow) * lda + kOff + sgr),
        (__attribute__((address_space(3))) uint32_t*)(&As[buf][srow * 32 + sgr]),
        16, 0, 0);
    __builtin_amdgcn_global_load_lds(
        (const __attribute__((address_space(1))) uint32_t*)
            (Bt + (size_t)(col0 + srow) * Ktot + k0 + sgr),
        (__attribute__((address_space(3))) uint32_t*)(&Bs[buf][srow * 32 + sgr]),
        16, 0, 0);
  };

  const int nk = Ktot >> 5;
  issue(0, 0);
  for (int k = 0; k < nk; k++) {
    const int cur = k & 1;
    if (k + 1 < nk) {
      issue(k + 1, cur ^ 1);
      asm volatile("s_waitcnt vmcnt(2)\ns_barrier" ::: "memory");
    } else {
      asm volatile("s_waitcnt vmcnt(0)\ns_barrier" ::: "memory");
    }
    bf16x8 a[2], b[4];
#pragma unroll
    for (int tm = 0; tm < 2; tm++)
      a[tm] = *(const bf16x8*)(&As[cur][(wr * 32 + tm * 16 + fm) * 32 + quad * 8]);
#pragma unroll
    for (int tn = 0; tn < 4; tn++)
      b[tn] = *(const bf16x8*)(&Bs[cur][(wc * 64 + tn * 16 + fm) * 32 + quad * 8]);
#pragma unroll
    for (int tm = 0; tm < 2; tm++)
#pragma unroll
      for (int tn = 0; tn < 4; tn++)
        acc[tm][tn] = __builtin_amdgcn_mfma_f32_16x16x32_bf16(a[tm], b[tn],
                                                              acc[tm][tn], 0, 0, 0);
    asm volatile("s_barrier" ::: "memory");
  }
}

// XCD-aware swizzle: gy is always 64 (M=8192). by = id%64, bx = id/64 makes
// all col-blocks of one row-block share id%8 -> same XCD (performance-only).
__device__ __forceinline__ void swizzled_block(int& row0, int& col0) {
  int id = blockIdx.x + gridDim.x * blockIdx.y;
  row0 = (id & 63) << 7;
  col0 = (id >> 6) << 7;
}

// Generic GEMM. ACT: 0 none, 1 relu, 2 tanh, 3 gelu(exact),
// 4 = split: cols < nsplit -> relu+bias0 -> C0; else tanh+bias1 -> C1.
template<int ACT>
__global__ __launch_bounds__(512, 4)
void mfma_gemm(const unsigned short* __restrict__ A0,
               const unsigned short* __restrict__ A1,
               int lda0, int lda1, int K0, int Ktot,
               const unsigned short* __restrict__ Bt,
               const float* __restrict__ bias0,
               const float* __restrict__ bias1, int nsplit,
               unsigned short* __restrict__ C0,
               unsigned short* __restrict__ C1, int ldc) {
  __shared__ unsigned short As[2][128 * 32];
  __shared__ unsigned short Bs[2][128 * 32];
  int row0, col0;
  swizzled_block(row0, col0);
  floatx4 acc[2][4];
#pragma unroll
  for (int tm = 0; tm < 2; tm++)
#pragma unroll
    for (int tn = 0; tn < 4; tn++) acc[tm][tn] = (floatx4){0.f, 0.f, 0.f, 0.f};
  gemm_core_db(A0, A1, lda0, lda1, K0, Ktot, Bt, row0, col0, As, Bs, acc);

  const int lane = threadIdx.x & 63, wave = threadIdx.x >> 6;
  const int wr = wave >> 1, wc = wave & 1;
  const int fm = lane & 15, quad = lane >> 4;
  const bool side = (ACT == 4) && (col0 >= nsplit);
  const float* bias = side ? bias1 : bias0;
  unsigned short* C = side ? C1 : C0;
  const int cbase = col0 - (side ? nsplit : 0);
#pragma unroll
  for (int tn = 0; tn < 4; tn++) {
    int col = cbase + wc * 64 + tn * 16 + fm;
    float bv = bias[col];
#pragma unroll
    for (int tm = 0; tm < 2; tm++) {
      int rbase = row0 + wr * 32 + tm * 16 + quad * 4;
#pragma unroll
      for (int r = 0; r < 4; r++) {
        float val = acc[tm][tn][r] + bv;
        if (ACT == 1) val = fmaxf(val, 0.0f);
        if (ACT == 2) val = tanhf(val);
        if (ACT == 3) val = 0.5f * val * (1.0f + erff(val * 0.70710678118654752f));
        if (ACT == 4) val = side ? tanhf(val) : fmaxf(val, 0.0f);
        C[(size_t)(rbase + r) * ldc + col] = f2bf(val);
      }
    }
  }
}

// z-batched pair of independent GEMMs (same shapes). No activation.
__global__ __launch_bounds__(512, 4)
void mfma_gemm_pair(const unsigned short* __restrict__ Aa,
                    const unsigned short* __restrict__ Ab,
                    const unsigned short* __restrict__ Bta,
                    const unsigned short* __restrict__ Btb,
                    const float* __restrict__ biasa,
                    const float* __restrict__ biasb,
                    unsigned short* __restrict__ Ca,
                    unsigned short* __restrict__ Cb,
                    int Ktot, int ldc) {
  __shared__ unsigned short As[2][128 * 32];
  __shared__ unsigned short Bs[2][128 * 32];
  const int z = blockIdx.z;
  const unsigned short* A = z ? Ab : Aa;
  const unsigned short* Bt = z ? Btb : Bta;
  const float* bias = z ? biasb : biasa;
  unsigned short* C = z ? Cb : Ca;
  int row0, col0;
  swizzled_block(row0, col0);
  floatx4 acc[2][4];
#pragma unroll
  for (int tm = 0; tm < 2; tm++)
#pragma unroll
    for (int tn = 0; tn < 4; tn++) acc[tm][tn] = (floatx4){0.f, 0.f, 0.f, 0.f};
  gemm_core_db(A, A, Ktot, Ktot, Ktot, Ktot, Bt, row0, col0, As, Bs, acc);

  const int lane = threadIdx.x & 63, wave = threadIdx.x >> 6;
  const int wr = wave >> 1, wc = wave & 1;
  const int fm = lane & 15, quad = lane >> 4;
#pragma unroll
  for (int tn = 0; tn < 4; tn++) {
    int col = col0 + wc * 64 + tn * 16 + fm;
    float bv = bias[col];
#pragma unroll
    for (int tm = 0; tm < 2; tm++) {
      int rbase = row0 + wr * 32 + tm * 16 + quad * 4;
#pragma unroll
      for (int r = 0; r < 4; r++)
        C[(size_t)(rbase + r) * ldc + col] = f2bf(acc[tm][tn][r] + bv);
    }
  }
}

// ---------------------------------------------------------------------------
// G7 fused: itf = hi @ Wi2 + bi2, then the full DDPM x-update in the
// epilogue. 64x128 tile, grid (4,128) = 512 blocks, 512 threads (8 waves of
// 32x32, wr=wave>>2, wc=wave&3). A-tile 64x32 (256 granules -> wave halves
// duplicate-load the same granules: benign identical DMA writes, keeps
// per-wave vmcnt uniform at 2). B-tile 128x32 (granule = tid). 16 normals
// per thread at 16 waves/CU (r7 had 64 at 4 waves/CU -> that's why it died).
// ---------------------------------------------------------------------------
__global__ __launch_bounds__(512, 4)
void mfma_gemm_update(const unsigned short* __restrict__ A,   // hi [8192,1024]
                      const unsigned short* __restrict__ Bt,  // Wi2_t [512][1024]
                      const float* __restrict__ bias,         // bi2
                      const unsigned short* __restrict__ d0,
                      const unsigned short* __restrict__ d1,
                      float* __restrict__ x,
                      unsigned short* __restrict__ xbf,
                      const float* __restrict__ a_amp,
                      const float* __restrict__ b_amp,
                      const float* __restrict__ ph,
                      float coh, float c1, float sqa, float sigma,
                      int add_noise, uint32_t k0, uint32_t k1) {
  __shared__ unsigned short As[2][64 * 32];
  __shared__ unsigned short Bs[2][128 * 32];
  const int tid = threadIdx.x;
  const int wave = tid >> 6, lane = tid & 63;
  const int wr = wave >> 2, wc = wave & 3;       // 32-row band / 32-col band
  const int fm = lane & 15, quad = lane >> 4;
  // swizzle: 128 row-blocks (64 rows each), 4 col-blocks (128 cols each)
  const int id = blockIdx.x + gridDim.x * blockIdx.y;
  const int row0 = (id & 127) << 6;
  const int col0 = (id >> 7) << 7;
  const int sArow = (tid & 255) >> 2;            // 0..63 (duplicated halves)
  const int sBrow = tid >> 2;                    // 0..127
  const int sgr = (tid & 3) * 8;

  auto issue = [&](int kt, int buf) {
    const int kk = kt * 32;
    __builtin_amdgcn_global_load_lds(
        (const __attribute__((address_space(1))) uint32_t*)
            (A + (size_t)(row0 + sArow) * 1024 + kk + sgr),
        (__attribute__((address_space(3))) uint32_t*)(&As[buf][sArow * 32 + sgr]),
        16, 0, 0);
    __builtin_amdgcn_global_load_lds(
        (const __attribute__((address_space(1))) uint32_t*)
            (Bt + (size_t)(col0 + sBrow) * 1024 + kk + sgr),
        (__attribute__((address_space(3))) uint32_t*)(&Bs[buf][sBrow * 32 + sgr]),
        16, 0, 0);
  };

  floatx4 acc[2][2];
#pragma unroll
  for (int tm = 0; tm < 2; tm++)
#pragma unroll
    for (int tn = 0; tn < 2; tn++) acc[tm][tn] = (floatx4){0.f, 0.f, 0.f, 0.f};

  const int nk = 32;  // K = 1024
  issue(0, 0);
  for (int k = 0; k < nk; k++) {
    const int cur = k & 1;
    if (k + 1 < nk) {
      issue(k + 1, cur ^ 1);
      asm volatile("s_waitcnt vmcnt(2)\ns_barrier" ::: "memory");
    } else {
      asm volatile("s_waitcnt vmcnt(0)\ns_barrier" ::: "memory");
    }
    bf16x8 a[2], b[2];
#pragma unroll
    for (int tm = 0; tm < 2; tm++)
      a[tm] = *(const bf16x8*)(&As[cur][(wr * 32 + tm * 16 + fm) * 32 + quad * 8]);
#pragma unroll
    for (int tn = 0; tn < 2; tn++)
      b[tn] = *(const bf16x8*)(&Bs[cur][(wc * 32 + tn * 16 + fm) * 32 + quad * 8]);
#pragma unroll
    for (int tm = 0; tm < 2; tm++)
#pragma unroll
      for (int tn = 0; tn < 2; tn++)
        acc[tm][tn] = __builtin_amdgcn_mfma_f32_16x16x32_bf16(a[tm], b[tn],
                                                              acc[tm][tn], 0, 0, 0);
    asm volatile("s_barrier" ::: "memory");
  }

  float aa = a_amp[0], bb = b_amp[0], pc = ph[0];
  float a2 = aa * aa, b2 = bb * bb, s = a2 + b2;
  float p0 = a2 / s, p1 = b2 / s;
  float sp0 = sqrtf(p0), sp1 = sqrtf(p1);
  float qi = 2.0f * sqrtf(p0 * p1) * pc * coh;
  float nscale = sigma + 0.1f * fabsf(qi);

#pragma unroll
  for (int tn = 0; tn < 2; tn++) {
    int col = col0 + wc * 32 + tn * 16 + fm;
    float bv = bias[col];
#pragma unroll
    for (int tm = 0; tm < 2; tm++) {
      int rbase = row0 + wr * 32 + tm * 16 + quad * 4;
#pragma unroll
      for (int r = 0; r < 4; r++) {
        int row = rbase + r;
        size_t i = (size_t)row * 512 + col;
        float itf = acc[tm][tn][r] + bv;
        float den = sp0 * bf2f(d0[i]) + sp1 * bf2f(d1[i]) + qi * itf;
        float xn = (x[i] - c1 * den) / sqa;
        if (add_noise) xn += nscale * tf_normal(k0, k1, (uint32_t)i);
        x[i] = xn;
        xbf[i] = f2bf(xn);
      }
    }
  }
}

__global__ void init_normal_kernel(float* __restrict__ x,
                                   unsigned short* __restrict__ xbf,
                                   uint32_t k0, uint32_t k1, int n) {
  int i = blockIdx.x * blockDim.x + threadIdx.x;
  if (i >= n) return;
  float v = tf_normal(k0, k1, (uint32_t)i);
  x[i] = v;
  xbf[i] = f2bf(v);
}

__global__ void final_kernel(const float* __restrict__ x,
                             const float* __restrict__ real,
                             float* __restrict__ out,
                             const float* __restrict__ a_amp,
                             const float* __restrict__ b_amp,
                             uint32_t k0, uint32_t k1, int n) {
  int i = blockIdx.x * blockDim.x + threadIdx.x;
  if (i >= n) return;
  float aa = a_amp[0], bb = b_amp[0];
  float a2 = aa * aa, b2 = bb * bb;
  float p0 = a2 / (a2 + b2);
  uint32_t o0, o1;
  tf2x32(k0, k1, 0u, 0u, o0, o1);
  uint32_t bits = o0 ^ o1;
  float u = __uint_as_float(0x3F800000u | (bits >> 9)) - 1.0f;
  float xv = x[i];
  out[i] = (u < p0) ? (0.7f * xv + 0.3f * real[i]) : xv;
}

extern "C" void kernel_launch(void* const* d_in, const int* in_sizes, int n_in,
                              void* d_out, int out_size, void* d_ws,
                              size_t ws_size, hipStream_t stream) {
  const float* real = (const float*)d_in[0];
  const float* Wq  = (const float*)d_in[2];
  const float* bq  = (const float*)d_in[3];
  const float* W01 = (const float*)d_in[4];
  const float* b01 = (const float*)d_in[5];
  const float* W02 = (const float*)d_in[6];
  const float* b02 = (const float*)d_in[7];
  const float* W11 = (const float*)d_in[8];
  const float* b11 = (const float*)d_in[9];
  const float* W12 = (const float*)d_in[10];
  const float* b12 = (const float*)d_in[11];
  const float* Wi1 = (const float*)d_in[12];
  const float* bi1 = (const float*)d_in[13];
  const float* Wi2 = (const float*)d_in[14];
  const float* bi2 = (const float*)d_in[15];
  const float* a_amp = (const float*)d_in[16];
  const float* b_amp = (const float*)d_in[17];
  const float* ph    = (const float*)d_in[18];

  const int Nn = 8192, F = 512, H = 1024;
  const int nElem = Nn * F;  // 4,194,304
  const int NSPLIT_OFF = 1 << 30;

  // workspace layout
  char* ws = (char*)d_ws;
  float* x = (float*)ws;                                   ws += (size_t)nElem * 4;
  unsigned short* xbf = (unsigned short*)ws;               ws += (size_t)nElem * 2;
  unsigned short* qf  = (unsigned short*)ws;               ws += (size_t)Nn * H * 2;
  unsigned short* h0  = (unsigned short*)ws;               ws += (size_t)Nn * H * 2;
  unsigned short* h1  = (unsigned short*)ws;               ws += (size_t)Nn * H * 2;
  unsigned short* d0  = (unsigned short*)ws;               ws += (size_t)nElem * 2;
  unsigned short* d1  = (unsigned short*)ws;               ws += (size_t)nElem * 2;
  unsigned short* Wq_t  = (unsigned short*)ws;             ws += (size_t)F * H * 2;
  unsigned short* WA_t  = (unsigned short*)ws;             ws += (size_t)(2 * H) * H * 2; // [W01_t ; W11_t]
  unsigned short* W02_t = (unsigned short*)ws;             ws += (size_t)H * F * 2;
  unsigned short* W12_t = (unsigned short*)ws;             ws += (size_t)H * F * 2;
  unsigned short* Wi1_t = (unsigned short*)ws;             ws += (size_t)(2 * F) * H * 2;
  unsigned short* Wi2_t = (unsigned short*)ws;             ws += (size_t)H * F * 2;

  dim3 tb(256);
  transpose_bf16_kernel<<<dim3(F / 32, H / 32), tb, 0, stream>>>(Wq, Wq_t, F, H);
  transpose_bf16_kernel<<<dim3(H / 32, H / 32), tb, 0, stream>>>(W01, WA_t, H, H);
  transpose_bf16_kernel<<<dim3(H / 32, H / 32), tb, 0, stream>>>(W11, WA_t + (size_t)H * H, H, H);
  transpose_bf16_kernel<<<dim3(H / 32, F / 32), tb, 0, stream>>>(W02, W02_t, H, F);
  transpose_bf16_kernel<<<dim3(H / 32, F / 32), tb, 0, stream>>>(W12, W12_t, H, F);
  transpose_bf16_kernel<<<dim3(2 * F / 32, H / 32), tb, 0, stream>>>(Wi1, Wi1_t, 2 * F, H);
  transpose_bf16_kernel<<<dim3(H / 32, F / 32), tb, 0, stream>>>(Wi2, Wi2_t, H, F);

  uint32_t kx0, kx1; tf2x32(0u, 1u, 0u, 10000u, kx0, kx1);
  init_normal_kernel<<<(nElem + 255) / 256, 256, 0, stream>>>(x, xbf, kx0, kx1, nElem);

  float sched[100];
  for (int i = 0; i < 100; i++)
    sched[i] = (float)(1e-4 + (0.02 - 1e-4) * (double)i / 99.0);
  const float decay = expf(-0.1f);
  float coh = 1.0f;

  dim3 blk(512);
  dim3 g1(H / 128, 64);            // 512 blocks
  dim3 g2(2 * H / 128, 64);        // 1024 blocks
  dim3 g45(F / 128, 64, 2);        // 512 blocks
  dim3 g6(H / 128, 64);            // 512 blocks
  dim3 g7(F / 128, Nn / 64);       // (4,128) = 512 blocks, 64x128 tiles

  for (int j = 0; j < 50; j++) {
    int t = 49 - j;
    // G1: qf = relu(x @ Wq + bq)
    mfma_gemm<1><<<g1, blk, 0, stream>>>(xbf, xbf, F, F, F, F, Wq_t,
                                         bq, nullptr, NSPLIT_OFF, qf, nullptr, H);
    // G2 merged: h0 = relu(qf@W01+b01), h1 = tanh(qf@W11+b11), N=2048 GEMM
    mfma_gemm<4><<<g2, blk, 0, stream>>>(qf, qf, H, H, H, H, WA_t,
                                         b01, b11, H, h0, h1, H);
    // G4/G5 z-batched: d0 = h0@W02+b02 ; d1 = h1@W12+b12
    mfma_gemm_pair<<<g45, blk, 0, stream>>>(h0, h1, W02_t, W12_t, b02, b12,
                                            d0, d1, H, F);
    // G6: qf(reused) = gelu([d0|d1] @ Wi1 + bi1)
    mfma_gemm<3><<<g6, blk, 0, stream>>>(d0, d1, F, F, F, 2 * F, Wi1_t,
                                         bi1, nullptr, NSPLIT_OFF, qf, nullptr, H);

    float schedt = sched[t];
    float alphaf = fmaxf(1.0f - schedt, 1e-8f);
    float one_m_alpha = 1.0f - alphaf;
    float sqrt_1ma = sqrtf(fmaxf(one_m_alpha, 1e-8f));
    float c1 = one_m_alpha / sqrt_1ma;
    float sqa = sqrtf(alphaf);
    float sigma = 0.0f;
    if (t > 0) {
      float ap = 1.0f - sched[t - 1];
      sigma = sqrtf(fmaxf((1.0f - ap) / one_m_alpha * (1.0f - alphaf / ap), 0.0f));
    }
    uint32_t kt0, kt1; tf2x32(0u, 1u, 0u, (uint32_t)t, kt0, kt1);
    // G7 fused: itf = qf @ Wi2 + bi2  +  DDPM update of x/xbf
    mfma_gemm_update<<<g7, blk, 0, stream>>>(
        qf, Wi2_t, bi2, d0, d1, x, xbf, a_amp, b_amp, ph, coh, c1, sqa, sigma,
        (t > 0) ? 1 : 0, kt0, kt1);
    coh *= decay;
  }

  uint32_t ku0, ku1; tf2x32(0u, 1u, 0u, 99999u, ku0, ku1);
  final_kernel<<<(nElem + 255) / 256, 256, 0, stream>>>(
      x, real, (float*)d_out, a_amp, b_amp, ku0, ku1, nElem);
}